// Round 1
// baseline (21993.880 us; speedup 1.0000x reference)
//
#include <hip/hip_runtime.h>
#include <hip/hip_bf16.h>

// ---------------------------------------------------------------------------
// HypergraphConv x2 + PReLU + residual, f32 baseline.
//   conv: xt = x@W ; m = segsum(xt[src] by dst)*Binv ; out = segsum(m[dst] by src)*Dinv + b
//   h = prelu(conv1(x)) ; out = prelu(conv2(h) + x)
// Workspace: bufA (102.4MB) | bufB (102.4MB) | Dinv (400KB) | Binv (400KB)
// ---------------------------------------------------------------------------

#define F_DIM 256

// ---- degree histogram ------------------------------------------------------
__global__ void degrees_kernel(const int* __restrict__ src, const int* __restrict__ dst,
                               float* __restrict__ D, float* __restrict__ B, int nnz) {
    int i = blockIdx.x * blockDim.x + threadIdx.x;
    int stride = gridDim.x * blockDim.x;
    for (; i < nnz; i += stride) {
        atomicAdd(&D[src[i]], 1.0f);
        atomicAdd(&B[dst[i]], 1.0f);
    }
}

__global__ void invert_kernel(float* __restrict__ D, float* __restrict__ B, int n) {
    int i = blockIdx.x * blockDim.x + threadIdx.x;
    if (i < n) {
        float d = D[i]; D[i] = d > 0.f ? 1.f / d : 0.f;
        float b = B[i]; B[i] = b > 0.f ? 1.f / b : 0.f;
    }
}

// ---- f32 SGEMM: C[M,256] = A[M,256] @ B[256,256] ---------------------------
// 128x128 tile, 256 threads, 8x8 per thread, BK=8
__global__ __launch_bounds__(256) void sgemm256(const float* __restrict__ A,
                                                const float* __restrict__ B,
                                                float* __restrict__ C, int M) {
    constexpr int N = 256, K = 256;
    constexpr int BM = 128, BN = 128, BK = 8, TM = 8, TN = 8;
    __shared__ float As[BK][BM + 4];
    __shared__ float Bs[BK][BN + 4];
    const int tid = threadIdx.x;
    const int tx = tid & 15;        // N direction (16)
    const int ty = tid >> 4;        // M direction (16)
    const int bm = blockIdx.x * BM;
    const int bn = blockIdx.y * BN;

    // load maps
    const int ar = tid >> 1;              // 0..127 row in A tile
    const int ac = (tid & 1) * 4;         // 0 or 4, k offset
    const int br = tid >> 5;              // 0..7 k row in B tile
    const int bc = (tid & 31) * 4;        // 0..124 col

    float acc[TM][TN] = {};

    for (int k0 = 0; k0 < K; k0 += BK) {
        float4 av = make_float4(0.f, 0.f, 0.f, 0.f);
        int grow = bm + ar;
        if (grow < M) av = *(const float4*)(A + (size_t)grow * K + k0 + ac);
        float4 bv = *(const float4*)(B + (size_t)(k0 + br) * N + bn + bc);
        As[ac + 0][ar] = av.x;
        As[ac + 1][ar] = av.y;
        As[ac + 2][ar] = av.z;
        As[ac + 3][ar] = av.w;
        *(float4*)&Bs[br][bc] = bv;
        __syncthreads();
#pragma unroll
        for (int kk = 0; kk < BK; ++kk) {
            float a[TM], b[TN];
#pragma unroll
            for (int i = 0; i < TM; ++i) a[i] = As[kk][ty * TM + i];
#pragma unroll
            for (int j = 0; j < TN; ++j) b[j] = Bs[kk][tx * TN + j];
#pragma unroll
            for (int i = 0; i < TM; ++i)
#pragma unroll
                for (int j = 0; j < TN; ++j) acc[i][j] += a[i] * b[j];
        }
        __syncthreads();
    }

#pragma unroll
    for (int i = 0; i < TM; ++i) {
        int grow = bm + ty * TM + i;
        if (grow >= M) continue;
        float* crow = C + (size_t)grow * N + bn + tx * TN;
        *(float4*)(crow + 0) = make_float4(acc[i][0], acc[i][1], acc[i][2], acc[i][3]);
        *(float4*)(crow + 4) = make_float4(acc[i][4], acc[i][5], acc[i][6], acc[i][7]);
    }
}

// ---- edge scatter: dst_mat[sidx[e]] += src_mat[gidx[e]] * (scale?scale[gidx[e]]:1)
// one wave per edge, lane l handles floats [4l, 4l+4)
__global__ __launch_bounds__(256) void scatter_add_kernel(const float* __restrict__ src_mat,
                                                          float* __restrict__ dst_mat,
                                                          const int* __restrict__ gidx,
                                                          const int* __restrict__ sidx,
                                                          const float* __restrict__ scale,
                                                          int nnz) {
    int wave = (blockIdx.x * blockDim.x + threadIdx.x) >> 6;
    int lane = threadIdx.x & 63;
    int nwaves = (gridDim.x * blockDim.x) >> 6;
    for (int e = wave; e < nnz; e += nwaves) {
        int g = gidx[e];
        int s = sidx[e];
        float sc = scale ? scale[g] : 1.0f;
        float4 v = *(const float4*)(src_mat + (size_t)g * F_DIM + lane * 4);
        float* drow = dst_mat + (size_t)s * F_DIM + lane * 4;
        atomicAdd(drow + 0, v.x * sc);
        atomicAdd(drow + 1, v.y * sc);
        atomicAdd(drow + 2, v.z * sc);
        atomicAdd(drow + 3, v.w * sc);
    }
}

// ---- epilogues -------------------------------------------------------------
// h = prelu(h*Dinv[row] + b[col])
__global__ void finalize1_kernel(float* __restrict__ h, const float* __restrict__ Dinv,
                                 const float* __restrict__ b, const float* __restrict__ a,
                                 int M) {
    float alpha = a[0];
    size_t total = (size_t)M * (F_DIM / 4);
    size_t i = (size_t)blockIdx.x * blockDim.x + threadIdx.x;
    size_t stride = (size_t)gridDim.x * blockDim.x;
    float4* h4 = (float4*)h;
    const float4* b4 = (const float4*)b;
    for (; i < total; i += stride) {
        size_t row = i >> 6;              // /64
        int f4 = (int)(i & 63);
        float d = Dinv[row];
        float4 v = h4[i];
        float4 bb = b4[f4];
        v.x = v.x * d + bb.x; v.x = v.x >= 0.f ? v.x : alpha * v.x;
        v.y = v.y * d + bb.y; v.y = v.y >= 0.f ? v.y : alpha * v.y;
        v.z = v.z * d + bb.z; v.z = v.z >= 0.f ? v.z : alpha * v.z;
        v.w = v.w * d + bb.w; v.w = v.w >= 0.f ? v.w : alpha * v.w;
        h4[i] = v;
    }
}

// out = prelu(out*Dinv[row] + b[col] + x)
__global__ void finalize2_kernel(float* __restrict__ out, const float* __restrict__ Dinv,
                                 const float* __restrict__ b, const float* __restrict__ x,
                                 const float* __restrict__ a, int M) {
    float alpha = a[0];
    size_t total = (size_t)M * (F_DIM / 4);
    size_t i = (size_t)blockIdx.x * blockDim.x + threadIdx.x;
    size_t stride = (size_t)gridDim.x * blockDim.x;
    float4* o4 = (float4*)out;
    const float4* x4 = (const float4*)x;
    const float4* b4 = (const float4*)b;
    for (; i < total; i += stride) {
        size_t row = i >> 6;
        int f4 = (int)(i & 63);
        float d = Dinv[row];
        float4 v = o4[i];
        float4 bb = b4[f4];
        float4 xv = x4[i];
        v.x = v.x * d + bb.x + xv.x; v.x = v.x >= 0.f ? v.x : alpha * v.x;
        v.y = v.y * d + bb.y + xv.y; v.y = v.y >= 0.f ? v.y : alpha * v.y;
        v.z = v.z * d + bb.z + xv.z; v.z = v.z >= 0.f ? v.z : alpha * v.z;
        v.w = v.w * d + bb.w + xv.w; v.w = v.w >= 0.f ? v.w : alpha * v.w;
        o4[i] = v;
    }
}

// ---------------------------------------------------------------------------
extern "C" void kernel_launch(void* const* d_in, const int* in_sizes, int n_in,
                              void* d_out, int out_size, void* d_ws, size_t ws_size,
                              hipStream_t stream) {
    const float* x   = (const float*)d_in[0];
    const int*   ei  = (const int*)d_in[1];
    const float* W1  = (const float*)d_in[2];
    const float* b1  = (const float*)d_in[3];
    const float* W2  = (const float*)d_in[4];
    const float* b2  = (const float*)d_in[5];
    const float* a   = (const float*)d_in[6];
    float* out = (float*)d_out;

    const int M   = in_sizes[0] / F_DIM;   // 100000
    const int nnz = in_sizes[1] / 2;       // 1600000
    const int* src = ei;
    const int* dst = ei + nnz;

    const size_t nbuf = (size_t)M * F_DIM * sizeof(float);  // 102.4 MB
    float* bufA = (float*)d_ws;
    float* bufB = (float*)((char*)d_ws + nbuf);
    float* Dinv = (float*)((char*)d_ws + 2 * nbuf);
    float* Binv = Dinv + M;

    const dim3 blk(256);
    const dim3 gemm_grid((M + 127) / 128, F_DIM / 128);
    const int scat_blocks = 4096;
    const int elem_blocks = 4096;

    // degrees
    hipMemsetAsync(Dinv, 0, 2 * (size_t)M * sizeof(float), stream);
    degrees_kernel<<<2048, blk, 0, stream>>>(src, dst, Dinv, Binv, nnz);
    invert_kernel<<<(M + 255) / 256, blk, 0, stream>>>(Dinv, Binv, M);

    // ---- conv1 ----
    sgemm256<<<gemm_grid, blk, 0, stream>>>(x, W1, bufA, M);          // xt
    hipMemsetAsync(bufB, 0, nbuf, stream);
    scatter_add_kernel<<<scat_blocks, blk, 0, stream>>>(bufA, bufB, src, dst, nullptr, nnz);   // m raw
    hipMemsetAsync(bufA, 0, nbuf, stream);
    scatter_add_kernel<<<scat_blocks, blk, 0, stream>>>(bufB, bufA, dst, src, Binv, nnz);      // node acc (Binv fused)
    finalize1_kernel<<<elem_blocks, blk, 0, stream>>>(bufA, Dinv, b1, a, M);                   // h = prelu(..)

    // ---- conv2 ----
    sgemm256<<<gemm_grid, blk, 0, stream>>>(bufA, W2, bufB, M);       // xt2
    hipMemsetAsync(bufA, 0, nbuf, stream);
    scatter_add_kernel<<<scat_blocks, blk, 0, stream>>>(bufB, bufA, src, dst, nullptr, nnz);   // m2 raw
    hipMemsetAsync(out, 0, (size_t)out_size * sizeof(float), stream);
    scatter_add_kernel<<<scat_blocks, blk, 0, stream>>>(bufA, out, dst, src, Binv, nnz);       // acc into out
    finalize2_kernel<<<elem_blocks, blk, 0, stream>>>(out, Dinv, b2, x, a, M);                 // prelu(.. + x)
}

// Round 2
// 1877.421 us; speedup vs baseline: 11.7149x; 11.7149x over previous
//
#include <hip/hip_runtime.h>
#include <hip/hip_bf16.h>

// ---------------------------------------------------------------------------
// HypergraphConv x2 + PReLU + residual. R2: CSR pull-gather (no f32 atomics).
//   conv: xt = x@W ; m = segsum(xt[src] by dst)*Binv ; out = segsum(m[dst] by src)*Dinv + b
//   h = prelu(conv1(x)) ; out = prelu(conv2(h) + x)
//
// Workspace layout:
//   bufA (102.4MB) | bufB (102.4MB) | cntD | cntB | rowptrS | rowptrD |
//   curS | curD | adjS (6.4MB) | adjD (6.4MB) | bsum | Dinv | Binv
// ---------------------------------------------------------------------------

#define F_DIM 256

// ---- 1. histogram ----------------------------------------------------------
__global__ void hist_kernel(const int* __restrict__ src, const int* __restrict__ dst,
                            int* __restrict__ cntD, int* __restrict__ cntB, int nnz) {
    int i = blockIdx.x * blockDim.x + threadIdx.x;
    int stride = gridDim.x * blockDim.x;
    for (; i < nnz; i += stride) {
        atomicAdd(&cntD[src[i]], 1);
        atomicAdd(&cntB[dst[i]], 1);
    }
}

// ---- 2. exclusive scan (3 kernels; n padded to 1024-multiple, nb<=256) -----
// k1: per-block (1024 elems) reduce -> bsum[y][b]
__global__ __launch_bounds__(256) void scan_k1(const int* __restrict__ cntD,
                                               const int* __restrict__ cntB,
                                               int* __restrict__ bsum, int nb) {
    const int* cnt = blockIdx.y ? cntB : cntD;
    int t = threadIdx.x;
    int4 v = ((const int4*)cnt)[blockIdx.x * 256 + t];
    int s = v.x + v.y + v.z + v.w;
    __shared__ int sh[256];
    sh[t] = s; __syncthreads();
    for (int off = 128; off > 0; off >>= 1) {
        if (t < off) sh[t] += sh[t + off];
        __syncthreads();
    }
    if (t == 0) bsum[blockIdx.y * nb + blockIdx.x] = sh[0];
}

// k2: single block scans both bsum arrays (nb<=256) -> exclusive; totals -> rowptr[n]
__global__ __launch_bounds__(256) void scan_k2(int* __restrict__ bsum,
                                               int* __restrict__ rowptrS,
                                               int* __restrict__ rowptrD, int nb, int n) {
    __shared__ int sh[256];
    int t = threadIdx.x;
    for (int y = 0; y < 2; ++y) {
        int* bs = bsum + y * nb;
        int v = (t < nb) ? bs[t] : 0;
        sh[t] = v; __syncthreads();
        for (int off = 1; off < 256; off <<= 1) {
            int add = (t >= off) ? sh[t - off] : 0;
            __syncthreads();
            sh[t] += add;
            __syncthreads();
        }
        if (t < nb) bs[t] = sh[t] - v;       // exclusive block offset
        if (t == 0) (y ? rowptrD : rowptrS)[n] = sh[255];
        __syncthreads();
    }
}

// k3: per-block rescan 1024 elems, add block offset, write exclusive prefix
__global__ __launch_bounds__(256) void scan_k3(const int* __restrict__ cntD,
                                               const int* __restrict__ cntB,
                                               const int* __restrict__ bsum,
                                               int* __restrict__ rowptrS,
                                               int* __restrict__ rowptrD, int nb, int n) {
    const int* cnt = blockIdx.y ? cntB : cntD;
    int* rp = blockIdx.y ? rowptrD : rowptrS;
    int boff = bsum[blockIdx.y * nb + blockIdx.x];
    int t = threadIdx.x;
    int4 v = ((const int4*)cnt)[blockIdx.x * 256 + t];
    int s = v.x + v.y + v.z + v.w;
    __shared__ int sh[256];
    sh[t] = s; __syncthreads();
    for (int off = 1; off < 256; off <<= 1) {
        int add = (t >= off) ? sh[t - off] : 0;
        __syncthreads();
        sh[t] += add;
        __syncthreads();
    }
    int excl = sh[t] - s + boff;
    int base = blockIdx.x * 1024 + t * 4;
    if (base + 0 < n) rp[base + 0] = excl;
    if (base + 1 < n) rp[base + 1] = excl + v.x;
    if (base + 2 < n) rp[base + 2] = excl + v.x + v.y;
    if (base + 3 < n) rp[base + 3] = excl + v.x + v.y + v.z;
}

// ---- 3. inverse degrees from rowptr ----------------------------------------
__global__ void make_inv_kernel(const int* __restrict__ rowptrS, const int* __restrict__ rowptrD,
                                float* __restrict__ Dinv, float* __restrict__ Binv, int n) {
    int i = blockIdx.x * blockDim.x + threadIdx.x;
    if (i < n) {
        int d = rowptrS[i + 1] - rowptrS[i];
        int b = rowptrD[i + 1] - rowptrD[i];
        Dinv[i] = d > 0 ? 1.f / (float)d : 0.f;
        Binv[i] = b > 0 ? 1.f / (float)b : 0.f;
    }
}

// ---- 4. adjacency fill -----------------------------------------------------
__global__ void fill_adj_kernel(const int* __restrict__ src, const int* __restrict__ dst,
                                int* __restrict__ curS, int* __restrict__ curD,
                                int* __restrict__ adjS, int* __restrict__ adjD, int nnz) {
    int i = blockIdx.x * blockDim.x + threadIdx.x;
    int stride = gridDim.x * blockDim.x;
    for (; i < nnz; i += stride) {
        int s = src[i], d = dst[i];
        int ps = atomicAdd(&curS[s], 1);
        adjS[ps] = d;                       // CSR by src: stores dst (hyperedge) ids
        int pd = atomicAdd(&curD[d], 1);
        adjD[pd] = s;                       // CSR by dst: stores src (node) ids
    }
}

// ---- 5. pull gather: out[r] = f(scale[r] * sum_{j in adj[r]} src_mat[j]) ---
// one wave per row; lanes batch-load 64 adj entries, shfl-broadcast each.
__global__ __launch_bounds__(256) void gather_rows_kernel(const float* __restrict__ src_mat,
                                                          float* __restrict__ out_mat,
                                                          const int* __restrict__ rowptr,
                                                          const int* __restrict__ adj,
                                                          const float* __restrict__ scale,
                                                          const float* __restrict__ bias,
                                                          const float* __restrict__ residual,
                                                          const float* __restrict__ alpha_p,
                                                          int n) {
    int wid = (blockIdx.x * blockDim.x + threadIdx.x) >> 6;
    int lane = threadIdx.x & 63;
    if (wid >= n) return;
    int beg = rowptr[wid], end = rowptr[wid + 1];
    float4 acc = make_float4(0.f, 0.f, 0.f, 0.f);
    for (int b0 = beg; b0 < end; b0 += 64) {
        int cnt = min(64, end - b0);
        int myidx = (b0 + lane < end) ? adj[b0 + lane] : 0;
        for (int j = 0; j < cnt; ++j) {
            int idx = __shfl(myidx, j);
            float4 v = *(const float4*)(src_mat + (size_t)idx * F_DIM + lane * 4);
            acc.x += v.x; acc.y += v.y; acc.z += v.z; acc.w += v.w;
        }
    }
    float sc = scale[wid];
    acc.x *= sc; acc.y *= sc; acc.z *= sc; acc.w *= sc;
    if (bias) {
        float4 bb = ((const float4*)bias)[lane];
        acc.x += bb.x; acc.y += bb.y; acc.z += bb.z; acc.w += bb.w;
    }
    if (residual) {
        float4 xv = *(const float4*)(residual + (size_t)wid * F_DIM + lane * 4);
        acc.x += xv.x; acc.y += xv.y; acc.z += xv.z; acc.w += xv.w;
    }
    if (alpha_p) {
        float al = alpha_p[0];
        acc.x = acc.x >= 0.f ? acc.x : al * acc.x;
        acc.y = acc.y >= 0.f ? acc.y : al * acc.y;
        acc.z = acc.z >= 0.f ? acc.z : al * acc.z;
        acc.w = acc.w >= 0.f ? acc.w : al * acc.w;
    }
    *(float4*)(out_mat + (size_t)wid * F_DIM + lane * 4) = acc;
}

// ---- f32 SGEMM: C[M,256] = A[M,256] @ B[256,256] ---------------------------
__global__ __launch_bounds__(256) void sgemm256(const float* __restrict__ A,
                                                const float* __restrict__ B,
                                                float* __restrict__ C, int M) {
    constexpr int N = 256, K = 256;
    constexpr int BM = 128, BN = 128, BK = 8, TM = 8, TN = 8;
    __shared__ float As[BK][BM + 4];
    __shared__ float Bs[BK][BN + 4];
    const int tid = threadIdx.x;
    const int tx = tid & 15;
    const int ty = tid >> 4;
    const int bm = blockIdx.x * BM;
    const int bn = blockIdx.y * BN;

    const int ar = tid >> 1;
    const int ac = (tid & 1) * 4;
    const int br = tid >> 5;
    const int bc = (tid & 31) * 4;

    float acc[TM][TN] = {};

    for (int k0 = 0; k0 < K; k0 += BK) {
        float4 av = make_float4(0.f, 0.f, 0.f, 0.f);
        int grow = bm + ar;
        if (grow < M) av = *(const float4*)(A + (size_t)grow * K + k0 + ac);
        float4 bv = *(const float4*)(B + (size_t)(k0 + br) * N + bn + bc);
        As[ac + 0][ar] = av.x;
        As[ac + 1][ar] = av.y;
        As[ac + 2][ar] = av.z;
        As[ac + 3][ar] = av.w;
        *(float4*)&Bs[br][bc] = bv;
        __syncthreads();
#pragma unroll
        for (int kk = 0; kk < BK; ++kk) {
            float a[TM], b[TN];
#pragma unroll
            for (int i = 0; i < TM; ++i) a[i] = As[kk][ty * TM + i];
#pragma unroll
            for (int j = 0; j < TN; ++j) b[j] = Bs[kk][tx * TN + j];
#pragma unroll
            for (int i = 0; i < TM; ++i)
#pragma unroll
                for (int j = 0; j < TN; ++j) acc[i][j] += a[i] * b[j];
        }
        __syncthreads();
    }

#pragma unroll
    for (int i = 0; i < TM; ++i) {
        int grow = bm + ty * TM + i;
        if (grow >= M) continue;
        float* crow = C + (size_t)grow * N + bn + tx * TN;
        *(float4*)(crow + 0) = make_float4(acc[i][0], acc[i][1], acc[i][2], acc[i][3]);
        *(float4*)(crow + 4) = make_float4(acc[i][4], acc[i][5], acc[i][6], acc[i][7]);
    }
}

// ---------------------------------------------------------------------------
extern "C" void kernel_launch(void* const* d_in, const int* in_sizes, int n_in,
                              void* d_out, int out_size, void* d_ws, size_t ws_size,
                              hipStream_t stream) {
    const float* x   = (const float*)d_in[0];
    const int*   ei  = (const int*)d_in[1];
    const float* W1  = (const float*)d_in[2];
    const float* b1  = (const float*)d_in[3];
    const float* W2  = (const float*)d_in[4];
    const float* b2  = (const float*)d_in[5];
    const float* a   = (const float*)d_in[6];
    float* out = (float*)d_out;

    const int M   = in_sizes[0] / F_DIM;   // 100000
    const int nnz = in_sizes[1] / 2;       // 1600000
    const int* src = ei;
    const int* dst = ei + nnz;

    const int NPAD = ((M + 1023) / 1024) * 1024;    // 100352
    const int nb = NPAD / 1024;                      // 98 (<=256 required)

    char* p = (char*)d_ws;
    const size_t nbuf = (size_t)M * F_DIM * sizeof(float);  // 102.4 MB
    float* bufA = (float*)p;               p += nbuf;
    float* bufB = (float*)p;               p += nbuf;
    int* cntD    = (int*)p;                p += (size_t)NPAD * 4;
    int* cntB    = (int*)p;                p += (size_t)NPAD * 4;
    int* rowptrS = (int*)p;                p += ((size_t)(M + 1) * 4 + 15) & ~15ull;
    int* rowptrD = (int*)p;                p += ((size_t)(M + 1) * 4 + 15) & ~15ull;
    int* curS    = (int*)p;                p += (size_t)M * 4;
    int* curD    = (int*)p;                p += (size_t)M * 4;
    int* adjS    = (int*)p;                p += (size_t)nnz * 4;
    int* adjD    = (int*)p;                p += (size_t)nnz * 4;
    int* bsum    = (int*)p;                p += ((size_t)2 * nb * 4 + 15) & ~15ull;
    float* Dinv  = (float*)p;              p += (size_t)M * 4;
    float* Binv  = (float*)p;              p += (size_t)M * 4;

    const dim3 blk(256);
    const dim3 gemm_grid((M + 127) / 128, F_DIM / 128);
    const int gather_blocks = (M + 3) / 4;   // 4 waves (rows) per 256-thr block

    // ---- build CSR (both directions) + inverse degrees ----
    hipMemsetAsync(cntD, 0, 2 * (size_t)NPAD * 4, stream);   // cntD & cntB contiguous
    hist_kernel<<<2048, blk, 0, stream>>>(src, dst, cntD, cntB, nnz);
    scan_k1<<<dim3(nb, 2), blk, 0, stream>>>(cntD, cntB, bsum, nb);
    scan_k2<<<1, blk, 0, stream>>>(bsum, rowptrS, rowptrD, nb, M);
    scan_k3<<<dim3(nb, 2), blk, 0, stream>>>(cntD, cntB, bsum, rowptrS, rowptrD, nb, M);
    make_inv_kernel<<<(M + 255) / 256, blk, 0, stream>>>(rowptrS, rowptrD, Dinv, Binv, M);
    hipMemcpyAsync(curS, rowptrS, (size_t)M * 4, hipMemcpyDeviceToDevice, stream);
    hipMemcpyAsync(curD, rowptrD, (size_t)M * 4, hipMemcpyDeviceToDevice, stream);
    fill_adj_kernel<<<2048, blk, 0, stream>>>(src, dst, curS, curD, adjS, adjD, nnz);

    // ---- conv1 ----
    sgemm256<<<gemm_grid, blk, 0, stream>>>(x, W1, bufA, M);                       // xt
    gather_rows_kernel<<<gather_blocks, blk, 0, stream>>>(bufA, bufB, rowptrD, adjD,
                                                          Binv, nullptr, nullptr, nullptr, M);  // m
    gather_rows_kernel<<<gather_blocks, blk, 0, stream>>>(bufB, bufA, rowptrS, adjS,
                                                          Dinv, b1, nullptr, a, M);             // h = prelu(.)

    // ---- conv2 ----
    sgemm256<<<gemm_grid, blk, 0, stream>>>(bufA, W2, bufB, M);                    // xt2
    gather_rows_kernel<<<gather_blocks, blk, 0, stream>>>(bufB, bufA, rowptrD, adjD,
                                                          Binv, nullptr, nullptr, nullptr, M);  // m2
    gather_rows_kernel<<<gather_blocks, blk, 0, stream>>>(bufA, out, rowptrS, adjS,
                                                          Dinv, b2, x, a, M);                   // prelu(. + x)
}

// Round 4
// 1672.465 us; speedup vs baseline: 13.1506x; 1.1225x over previous
//
#include <hip/hip_runtime.h>
#include <hip/hip_bf16.h>

// ---------------------------------------------------------------------------
// HypergraphConv x2 + PReLU + residual. R4: f32 intermediates + split-bf16
// MFMA GEMM (A@W = Ahi@Whi + Ahi@Wlo + Alo@Whi; f32-accurate).
//   conv: xt = x@W ; m = segsum(xt[src] by dst)*Binv ; out = segsum(m[dst] by src)*Dinv + b
//   h = prelu(conv1(x)) ; out = prelu(conv2(h) + x)
// ---------------------------------------------------------------------------

#define F_DIM 256

using bf16x8 = __attribute__((ext_vector_type(8))) short;
using f32x4  = __attribute__((ext_vector_type(4))) float;

__device__ __forceinline__ short f2bf(float f) {
    __hip_bfloat16 h = __float2bfloat16(f);
    return *reinterpret_cast<short*>(&h);
}
__device__ __forceinline__ float bf2f(short s) {
    return __uint_as_float(((unsigned)(unsigned short)s) << 16);
}

// ---- 1. histogram ----------------------------------------------------------
__global__ void hist_kernel(const int* __restrict__ src, const int* __restrict__ dst,
                            int* __restrict__ cntD, int* __restrict__ cntB, int nnz) {
    int i = blockIdx.x * blockDim.x + threadIdx.x;
    int stride = gridDim.x * blockDim.x;
    for (; i < nnz; i += stride) {
        atomicAdd(&cntD[src[i]], 1);
        atomicAdd(&cntB[dst[i]], 1);
    }
}

// ---- 2. exclusive scan -----------------------------------------------------
__global__ __launch_bounds__(256) void scan_k1(const int* __restrict__ cntD,
                                               const int* __restrict__ cntB,
                                               int* __restrict__ bsum, int nb) {
    const int* cnt = blockIdx.y ? cntB : cntD;
    int t = threadIdx.x;
    int4 v = ((const int4*)cnt)[blockIdx.x * 256 + t];
    int s = v.x + v.y + v.z + v.w;
    __shared__ int sh[256];
    sh[t] = s; __syncthreads();
    for (int off = 128; off > 0; off >>= 1) {
        if (t < off) sh[t] += sh[t + off];
        __syncthreads();
    }
    if (t == 0) bsum[blockIdx.y * nb + blockIdx.x] = sh[0];
}

__global__ __launch_bounds__(256) void scan_k2(int* __restrict__ bsum,
                                               int* __restrict__ rowptrS,
                                               int* __restrict__ rowptrD, int nb, int n) {
    __shared__ int sh[256];
    int t = threadIdx.x;
    for (int y = 0; y < 2; ++y) {
        int* bs = bsum + y * nb;
        int v = (t < nb) ? bs[t] : 0;
        sh[t] = v; __syncthreads();
        for (int off = 1; off < 256; off <<= 1) {
            int add = (t >= off) ? sh[t - off] : 0;
            __syncthreads();
            sh[t] += add;
            __syncthreads();
        }
        if (t < nb) bs[t] = sh[t] - v;
        if (t == 0) (y ? rowptrD : rowptrS)[n] = sh[255];
        __syncthreads();
    }
}

__global__ __launch_bounds__(256) void scan_k3(const int* __restrict__ cntD,
                                               const int* __restrict__ cntB,
                                               const int* __restrict__ bsum,
                                               int* __restrict__ rowptrS,
                                               int* __restrict__ rowptrD, int nb, int n) {
    const int* cnt = blockIdx.y ? cntB : cntD;
    int* rp = blockIdx.y ? rowptrD : rowptrS;
    int boff = bsum[blockIdx.y * nb + blockIdx.x];
    int t = threadIdx.x;
    int4 v = ((const int4*)cnt)[blockIdx.x * 256 + t];
    int s = v.x + v.y + v.z + v.w;
    __shared__ int sh[256];
    sh[t] = s; __syncthreads();
    for (int off = 1; off < 256; off <<= 1) {
        int add = (t >= off) ? sh[t - off] : 0;
        __syncthreads();
        sh[t] += add;
        __syncthreads();
    }
    int excl = sh[t] - s + boff;
    int base = blockIdx.x * 1024 + t * 4;
    if (base + 0 < n) rp[base + 0] = excl;
    if (base + 1 < n) rp[base + 1] = excl + v.x;
    if (base + 2 < n) rp[base + 2] = excl + v.x + v.y;
    if (base + 3 < n) rp[base + 3] = excl + v.x + v.y + v.z;
}

// ---- 3. inverse degrees ----------------------------------------------------
__global__ void make_inv_kernel(const int* __restrict__ rowptrS, const int* __restrict__ rowptrD,
                                float* __restrict__ Dinv, float* __restrict__ Binv, int n) {
    int i = blockIdx.x * blockDim.x + threadIdx.x;
    if (i < n) {
        int d = rowptrS[i + 1] - rowptrS[i];
        int b = rowptrD[i + 1] - rowptrD[i];
        Dinv[i] = d > 0 ? 1.f / (float)d : 0.f;
        Binv[i] = b > 0 ? 1.f / (float)b : 0.f;
    }
}

// ---- 4. adjacency fill -----------------------------------------------------
__global__ void fill_adj_kernel(const int* __restrict__ src, const int* __restrict__ dst,
                                int* __restrict__ curS, int* __restrict__ curD,
                                int* __restrict__ adjS, int* __restrict__ adjD, int nnz) {
    int i = blockIdx.x * blockDim.x + threadIdx.x;
    int stride = gridDim.x * blockDim.x;
    for (; i < nnz; i += stride) {
        int s = src[i], d = dst[i];
        int ps = atomicAdd(&curS[s], 1);
        adjS[ps] = d;
        int pd = atomicAdd(&curD[d], 1);
        adjD[pd] = s;
    }
}

// ---- 5. W prepack: f32 -> bf16 hi/lo MFMA B-fragment order -----------------
// frag blob (kt,nt): 64 lanes x 8; lane holds B[kt*32+(lane>>4)*8+j][nt*16+(lane&15)]
__global__ void prepack_w_kernel(const float* __restrict__ W,
                                 short* __restrict__ Whi, short* __restrict__ Wlo) {
    int lane = threadIdx.x;            // 64
    int nt = blockIdx.x;               // 16
    int kt = blockIdx.y;               // 8
    int col = nt * 16 + (lane & 15);
    int krow = kt * 32 + (lane >> 4) * 8;
    size_t o = ((size_t)(kt * 16 + nt) * 64 + lane) * 8;
#pragma unroll
    for (int j = 0; j < 8; ++j) {
        float w = W[(size_t)(krow + j) * 256 + col];
        short hi = f2bf(w);
        Whi[o + j] = hi;
        Wlo[o + j] = f2bf(w - bf2f(hi));
    }
}

// ---- 6. split-bf16 MFMA GEMM: C[M,256](f32) = A[M,256](f32) @ W ------------
// block 256 thr = 4 waves (2x2 of 64x64); tile 128(M) x 128(N); K-loop 8x32.
__global__ __launch_bounds__(256) void gemm_mfma_split(const float* __restrict__ A,
                                                       const short* __restrict__ Whi,
                                                       const short* __restrict__ Wlo,
                                                       float* __restrict__ C, int M) {
    __shared__ short AsHi[4][128][8];    // 8 KB
    __shared__ short AsLo[4][128][8];    // 8 KB
    const int tid = threadIdx.x;
    const int w = tid >> 6, lane = tid & 63;
    const int quad = lane >> 4, l16 = lane & 15;
    const int bm = blockIdx.x * 128;
    const int bn_t = blockIdx.y * 8;             // n-tile base (16-col tiles)
    const int wm = (w & 1) * 64;
    const int wnt = (w >> 1) * 4;

    f32x4 acc[4][4] = {};

    for (int kt = 0; kt < 8; ++kt) {
        __syncthreads();
        // stage A tile: 128 rows x 32 k, f32 -> bf16 hi/lo
#pragma unroll
        for (int i = 0; i < 2; ++i) {
            int idx = tid + i * 256;
            int row = idx >> 2, seg = idx & 3;
            int grow = bm + row; if (grow >= M) grow = M - 1;
            const float* ap = A + (size_t)grow * 256 + kt * 32 + seg * 8;
            float4 v0 = *(const float4*)ap;
            float4 v1 = *(const float4*)(ap + 4);
            float vv[8] = {v0.x, v0.y, v0.z, v0.w, v1.x, v1.y, v1.z, v1.w};
            union { short s[8]; int4 q; } uh, ul;
#pragma unroll
            for (int e = 0; e < 8; ++e) {
                short hi = f2bf(vv[e]);
                uh.s[e] = hi;
                ul.s[e] = f2bf(vv[e] - bf2f(hi));
            }
            *(int4*)&AsHi[seg][row][0] = uh.q;
            *(int4*)&AsLo[seg][row][0] = ul.q;
        }
        __syncthreads();

        bf16x8 ahi[4], alo[4];
#pragma unroll
        for (int i = 0; i < 4; ++i) {
            ahi[i] = *(const bf16x8*)&AsHi[quad][wm + i * 16 + l16][0];
            alo[i] = *(const bf16x8*)&AsLo[quad][wm + i * 16 + l16][0];
        }

#pragma unroll
        for (int j = 0; j < 4; ++j) {
            int nt = bn_t + wnt + j;
            size_t off = ((size_t)(kt * 16 + nt) * 64 + lane) * 8;
            bf16x8 bhi = *(const bf16x8*)(Whi + off);
            bf16x8 blo = *(const bf16x8*)(Wlo + off);
#pragma unroll
            for (int i = 0; i < 4; ++i) {
                acc[i][j] = __builtin_amdgcn_mfma_f32_16x16x32_bf16(ahi[i], bhi, acc[i][j], 0, 0, 0);
                acc[i][j] = __builtin_amdgcn_mfma_f32_16x16x32_bf16(ahi[i], blo, acc[i][j], 0, 0, 0);
                acc[i][j] = __builtin_amdgcn_mfma_f32_16x16x32_bf16(alo[i], bhi, acc[i][j], 0, 0, 0);
            }
        }
    }

    // epilogue: C[row][col] = acc (f32); row = wm + i*16 + quad*4 + r, col per tile
#pragma unroll
    for (int i = 0; i < 4; ++i) {
#pragma unroll
        for (int j = 0; j < 4; ++j) {
            int col = (bn_t + wnt + j) * 16 + l16;
            int row0 = bm + wm + i * 16 + quad * 4;
#pragma unroll
            for (int r = 0; r < 4; ++r) {
                int row = row0 + r;
                if (row < M) C[(size_t)row * 256 + col] = acc[i][j][r];
            }
        }
    }
}

// ---- 7. pull gather (f32): out[r] = f(scale[r]*sum_{j in adj[r]} src[j]) ---
__global__ __launch_bounds__(256) void gather_rows_kernel(const float* __restrict__ src_mat,
                                                          float* __restrict__ out_mat,
                                                          const int* __restrict__ rowptr,
                                                          const int* __restrict__ adj,
                                                          const float* __restrict__ scale,
                                                          const float* __restrict__ bias,
                                                          const float* __restrict__ residual,
                                                          const float* __restrict__ alpha_p,
                                                          int n) {
    int wid = (blockIdx.x * blockDim.x + threadIdx.x) >> 6;
    int lane = threadIdx.x & 63;
    if (wid >= n) return;
    int beg = rowptr[wid], end = rowptr[wid + 1];
    float4 acc = make_float4(0.f, 0.f, 0.f, 0.f);
    for (int b0 = beg; b0 < end; b0 += 64) {
        int cnt = min(64, end - b0);
        int myidx = (b0 + lane < end) ? adj[b0 + lane] : 0;
        for (int j = 0; j < cnt; ++j) {
            int idx = __shfl(myidx, j);
            float4 v = *(const float4*)(src_mat + (size_t)idx * F_DIM + lane * 4);
            acc.x += v.x; acc.y += v.y; acc.z += v.z; acc.w += v.w;
        }
    }
    float sc = scale[wid];
    acc.x *= sc; acc.y *= sc; acc.z *= sc; acc.w *= sc;
    if (bias) {
        float4 bb = ((const float4*)bias)[lane];
        acc.x += bb.x; acc.y += bb.y; acc.z += bb.z; acc.w += bb.w;
    }
    if (residual) {
        float4 xv = *(const float4*)(residual + (size_t)wid * F_DIM + lane * 4);
        acc.x += xv.x; acc.y += xv.y; acc.z += xv.z; acc.w += xv.w;
    }
    if (alpha_p) {
        float al = alpha_p[0];
        acc.x = acc.x >= 0.f ? acc.x : al * acc.x;
        acc.y = acc.y >= 0.f ? acc.y : al * acc.y;
        acc.z = acc.z >= 0.f ? acc.z : al * acc.z;
        acc.w = acc.w >= 0.f ? acc.w : al * acc.w;
    }
    *(float4*)(out_mat + (size_t)wid * F_DIM + lane * 4) = acc;
}

// ---------------------------------------------------------------------------
extern "C" void kernel_launch(void* const* d_in, const int* in_sizes, int n_in,
                              void* d_out, int out_size, void* d_ws, size_t ws_size,
                              hipStream_t stream) {
    const float* x   = (const float*)d_in[0];
    const int*   ei  = (const int*)d_in[1];
    const float* W1  = (const float*)d_in[2];
    const float* b1  = (const float*)d_in[3];
    const float* W2  = (const float*)d_in[4];
    const float* b2  = (const float*)d_in[5];
    const float* a   = (const float*)d_in[6];
    float* out = (float*)d_out;

    const int M   = in_sizes[0] / F_DIM;   // 100000
    const int nnz = in_sizes[1] / 2;       // 1600000
    const int* src = ei;
    const int* dst = ei + nnz;

    const int NPAD = ((M + 1023) / 1024) * 1024;
    const int nb = NPAD / 1024;            // 98

    char* p = (char*)d_ws;
    const size_t nbuf = (size_t)M * F_DIM * sizeof(float);     // 102.4 MB
    const size_t wpk  = 8 * 16 * 64 * 8 * sizeof(short);        // 128 KB
    float* bufA = (float*)p;               p += nbuf;
    float* bufB = (float*)p;               p += nbuf;
    short* W1hi = (short*)p;               p += wpk;
    short* W1lo = (short*)p;               p += wpk;
    short* W2hi = (short*)p;               p += wpk;
    short* W2lo = (short*)p;               p += wpk;
    int* cntD    = (int*)p;                p += (size_t)NPAD * 4;
    int* cntB    = (int*)p;                p += (size_t)NPAD * 4;
    int* rowptrS = (int*)p;                p += ((size_t)(M + 1) * 4 + 15) & ~15ull;
    int* rowptrD = (int*)p;                p += ((size_t)(M + 1) * 4 + 15) & ~15ull;
    int* curS    = (int*)p;                p += (size_t)M * 4;
    int* curD    = (int*)p;                p += (size_t)M * 4;
    int* adjS    = (int*)p;                p += (size_t)nnz * 4;
    int* adjD    = (int*)p;                p += (size_t)nnz * 4;
    int* bsum    = (int*)p;                p += ((size_t)2 * nb * 4 + 15) & ~15ull;
    float* Dinv  = (float*)p;              p += (size_t)M * 4;
    float* Binv  = (float*)p;              p += (size_t)M * 4;

    const dim3 blk(256);
    const dim3 gemm_grid((M + 127) / 128, 2);
    const int gather_blocks = (M + 3) / 4;

    // ---- CSR build ----
    hipMemsetAsync(cntD, 0, 2 * (size_t)NPAD * 4, stream);
    hist_kernel<<<2048, blk, 0, stream>>>(src, dst, cntD, cntB, nnz);
    scan_k1<<<dim3(nb, 2), blk, 0, stream>>>(cntD, cntB, bsum, nb);
    scan_k2<<<1, blk, 0, stream>>>(bsum, rowptrS, rowptrD, nb, M);
    scan_k3<<<dim3(nb, 2), blk, 0, stream>>>(cntD, cntB, bsum, rowptrS, rowptrD, nb, M);
    make_inv_kernel<<<(M + 255) / 256, blk, 0, stream>>>(rowptrS, rowptrD, Dinv, Binv, M);
    hipMemcpyAsync(curS, rowptrS, (size_t)M * 4, hipMemcpyDeviceToDevice, stream);
    hipMemcpyAsync(curD, rowptrD, (size_t)M * 4, hipMemcpyDeviceToDevice, stream);
    fill_adj_kernel<<<2048, blk, 0, stream>>>(src, dst, curS, curD, adjS, adjD, nnz);

    // ---- weight prepack (hi/lo) ----
    prepack_w_kernel<<<dim3(16, 8), 64, 0, stream>>>(W1, W1hi, W1lo);
    prepack_w_kernel<<<dim3(16, 8), 64, 0, stream>>>(W2, W2hi, W2lo);

    // ---- conv1 ----
    gemm_mfma_split<<<gemm_grid, blk, 0, stream>>>(x, W1hi, W1lo, bufA, M);        // xt
    gather_rows_kernel<<<gather_blocks, blk, 0, stream>>>(bufA, bufB, rowptrD, adjD,
                                                          Binv, nullptr, nullptr, nullptr, M);  // m
    gather_rows_kernel<<<gather_blocks, blk, 0, stream>>>(bufB, bufA, rowptrS, adjS,
                                                          Dinv, b1, nullptr, a, M);             // h

    // ---- conv2 ----
    gemm_mfma_split<<<gemm_grid, blk, 0, stream>>>(bufA, W2hi, W2lo, bufB, M);     // xt2
    gather_rows_kernel<<<gather_blocks, blk, 0, stream>>>(bufB, bufA, rowptrD, adjD,
                                                          Binv, nullptr, nullptr, nullptr, M);  // m2
    gather_rows_kernel<<<gather_blocks, blk, 0, stream>>>(bufA, out, rowptrS, adjS,
                                                          Dinv, b2, x, a, M);                   // prelu(.+x)
}